// Round 6
// baseline (399.541 us; speedup 1.0000x reference)
//
#include <hip/hip_runtime.h>
#include <stdint.h>

typedef unsigned short u16;
typedef __attribute__((ext_vector_type(8))) __bf16 bf16x8;
typedef __attribute__((ext_vector_type(4))) __bf16 bf16x4;
typedef __attribute__((ext_vector_type(8))) unsigned short u16x8;
typedef __attribute__((ext_vector_type(4))) float f32x4;

// async global->LDS, 16B per lane. LDS dest is wave-uniform base + lane*16.
__device__ __forceinline__ void glds16(const u16* g, u16* l) {
  auto* gp = reinterpret_cast<const __attribute__((address_space(1))) unsigned*>(
      reinterpret_cast<uintptr_t>(g));
  auto* lp = reinterpret_cast<__attribute__((address_space(3))) unsigned*>(
      reinterpret_cast<uintptr_t>(l));
  __builtin_amdgcn_global_load_lds(gp, lp, 16, 0, 0);
}

// ---------------- shared gemm tile core (m97 structure) ----------------
// C[M][N] = A[M][K] @ BT[N][K]^T. 128x128 tile, 4 waves, 16x16x32 MFMA.
// LDS [128][32] bf16 unpadded, staged via global_load_lds width 16.
// mode 0: bf16 out; mode 1: f32 out + bias.
__device__ __forceinline__ void gemm_tile(const u16* __restrict__ A,
                                          const u16* __restrict__ BT,
                                          void* __restrict__ Cv,
                                          const float* __restrict__ bias,
                                          int N, int K, int mode, int br,
                                          int bc, u16* As, u16* Bs) {
  const int tid = threadIdx.x;
  const int lane = tid & 63, wave = tid >> 6;
  const int quad = lane >> 4, l16 = lane & 15;
  const int wm = (wave >> 1) * 64, wn = (wave & 1) * 64;

  f32x4 acc[4][4] = {};

  const int arow = wave * 32 + (lane >> 2);
  const int acol = (lane & 3) * 8;
  const u16* ap0 = A + (long)(br + arow) * K + acol;
  const u16* ap1 = ap0 + 16 * K;
  const u16* bp0 = BT + (long)(bc + arow) * K + acol;
  const u16* bp1 = bp0 + 16 * K;
  u16* al0 = As + wave * 1024;  // rows wave*32 .. +15
  u16* al1 = al0 + 512;         // rows wave*32+16 .. +31
  u16* bl0 = Bs + wave * 1024;
  u16* bl1 = bl0 + 512;

  for (int k0 = 0; k0 < K; k0 += 32) {
    glds16(ap0 + k0, al0);
    glds16(ap1 + k0, al1);
    glds16(bp0 + k0, bl0);
    glds16(bp1 + k0, bl1);
    __syncthreads();  // drains vmcnt before LDS reads
    bf16x8 af[4], bf[4];
#pragma unroll
    for (int i = 0; i < 4; ++i)
      af[i] = *(const bf16x8*)&As[(wm + i * 16 + l16) * 32 + quad * 8];
#pragma unroll
    for (int j = 0; j < 4; ++j)
      bf[j] = *(const bf16x8*)&Bs[(wn + j * 16 + l16) * 32 + quad * 8];
#pragma unroll
    for (int i = 0; i < 4; ++i)
#pragma unroll
      for (int j = 0; j < 4; ++j)
        acc[i][j] = __builtin_amdgcn_mfma_f32_16x16x32_bf16(af[i], bf[j],
                                                            acc[i][j], 0, 0, 0);
    __syncthreads();
  }

#pragma unroll
  for (int i = 0; i < 4; ++i)
#pragma unroll
    for (int j = 0; j < 4; ++j)
#pragma unroll
      for (int r = 0; r < 4; ++r) {
        int row = br + wm + i * 16 + quad * 4 + r;
        int col = bc + wn + j * 16 + l16;
        float v = acc[i][j][r];
        if (mode == 1) {
          ((float*)Cv)[(long)row * N + col] = v + bias[col];
        } else {
          ((__bf16*)Cv)[(long)row * N + col] = (__bf16)v;
        }
      }
}

// ---------------- prep: weight transposes + cvt of x batch 0 ----------------
// grid 672: [0,432) w_qkv 64x64 transpose tiles; [432,576) w_out; [576,672) cvt.
__device__ __forceinline__ void tp_tile(const float* __restrict__ src,
                                        u16* __restrict__ dst, int C, int Rd,
                                        int r0, int c0, u16* lds) {
  const int tid = threadIdx.x;
  {
    int r = tid >> 2, cb = (tid & 3) * 16;
#pragma unroll
    for (int k = 0; k < 4; ++k) {
      f32x4 v = *(const f32x4*)&src[(long)(r0 + r) * C + c0 + cb + k * 4];
      *(bf16x4*)&lds[r * 72 + cb + k * 4] = __builtin_convertvector(v, bf16x4);
    }
  }
  __syncthreads();
  {
    int c = tid >> 2, rb = (tid & 3) * 16;
    u16x8 o0, o1;
#pragma unroll
    for (int q = 0; q < 8; ++q) {
      o0[q] = lds[(rb + q) * 72 + c];
      o1[q] = lds[(rb + 8 + q) * 72 + c];
    }
    *(u16x8*)&dst[(long)(c0 + c) * Rd + r0 + rb] = o0;
    *(u16x8*)&dst[(long)(c0 + c) * Rd + r0 + rb + 8] = o1;
  }
}

__device__ __forceinline__ void cvt_role(const float* __restrict__ src,
                                         u16* __restrict__ dst, int bxl) {
  // 2048*768 = 1,572,864 elems; 96 blocks * 256 thr * 8 elems * 8 iters
  int base = (bxl * 256 + (int)threadIdx.x) * 8;
#pragma unroll
  for (int it = 0; it < 8; ++it, base += 196608) {
    f32x4 a = *(const f32x4*)&src[base];
    f32x4 b = *(const f32x4*)&src[base + 4];
    *(bf16x4*)&dst[base] = __builtin_convertvector(a, bf16x4);
    *(bf16x4*)&dst[base + 4] = __builtin_convertvector(b, bf16x4);
  }
}

__global__ __launch_bounds__(256) void prep_k(const float* __restrict__ w_qkv,
                                              const float* __restrict__ w_out,
                                              const float* __restrict__ x0,
                                              u16* __restrict__ wqkvT,
                                              u16* __restrict__ woutT,
                                              u16* __restrict__ xb) {
  __shared__ u16 lds[64 * 72];
  int bx = blockIdx.x;
  if (bx < 432) {  // w_qkv [768][2304] -> wqkvT [2304][768]
    int tr = bx / 36, tc = bx % 36;
    tp_tile(w_qkv, wqkvT, 2304, 768, tr * 64, tc * 64, lds);
  } else if (bx < 576) {  // w_out [768][768] -> woutT [768][768]
    int t = bx - 432;
    tp_tile(w_out, woutT, 768, 768, (t / 12) * 64, (t % 12) * 64, lds);
  } else {
    cvt_role(x0, xb, bx - 576);
  }
}

// ---------------- combo: gemm2(prev) + gemm_qk(cur) + gemm_vt(cur) ----------
// grid: g2n + (has_qkvt ? 288 : 0), g2n = has_g2 ? 96 : 0.
__global__ __launch_bounds__(256) void combo_gemm(
    const u16* __restrict__ attnb, float* __restrict__ out_prev,
    const float* __restrict__ bias, const u16* __restrict__ xb,
    const u16* __restrict__ wqkvT, const u16* __restrict__ woutT,
    u16* __restrict__ qkb, u16* __restrict__ vtb, int has_g2, int has_qkvt) {
  __shared__ __align__(16) u16 As[128 * 32];
  __shared__ __align__(16) u16 Bs[128 * 32];
  int bx = blockIdx.x;
  int g2n = has_g2 ? 96 : 0;
  if (bx < g2n) {
    // out_prev[2048][768] = attnb @ woutT + bias (fp32 out)
    gemm_tile(attnb, woutT, out_prev, bias, 768, 768, 1, (bx / 6) * 128,
              (bx % 6) * 128, As, Bs);
  } else if (has_qkvt) {
    int i2 = bx - g2n;
    if (i2 < 192) {
      // qkb[2048][1536] = xb @ wqkvT[0:1536]^T
      gemm_tile(xb, wqkvT, qkb, nullptr, 1536, 768, 0, (i2 / 12) * 128,
                (i2 % 12) * 128, As, Bs);
    } else {
      int i3 = i2 - 192;  // 0..95
      // vtb[768][2048] = wvT @ xb^T   (wvT = wqkvT + 1536*768)
      gemm_tile(wqkvT + 1536 * 768, xb, vtb, nullptr, 2048, 768, 0,
                (i3 / 16) * 128, (i3 % 16) * 128, As, Bs);
    }
  }
}

// ---------------- combo: attention(cur) + cvt(next) ----------------
// grid: 192 + (has_cvt ? 96 : 0). attn role identical math to round 5.
__global__ __launch_bounds__(256, 4) void combo_attn(
    const u16* __restrict__ qkb, const u16* __restrict__ vtb,
    u16* __restrict__ attnb, const float* __restrict__ xnext,
    u16* __restrict__ xb, int has_cvt) {
  const int LQ = 72;
  __shared__ __align__(16) u16 Ks[64 * LQ];
  __shared__ __align__(16) u16 Vs[64 * LQ];
  __shared__ __align__(16) u16 Ps[128 * LQ];

  int bx = blockIdx.x;
  if (bx >= 192) {
    if (has_cvt) cvt_role(xnext, xb, bx - 192);
    return;
  }
  const int qt = bx & 15;   // 0..15
  const int h = bx >> 4;    // 0..11
  const int tid = threadIdx.x;
  const int lane = tid & 63, wave = tid >> 6;
  const int quad = lane >> 4, l16 = lane & 15;
  const u16* vtb_h = vtb + (size_t)h * 64 * 2048;

  // stage Q tile into Ps
#pragma unroll
  for (int it = 0; it < 4; ++it) {
    int c = tid + it * 256;
    int m = c >> 3, off = (c & 7) * 8;
    *(u16x8*)&Ps[m * LQ + off] =
        *(const u16x8*)&qkb[(long)(qt * 128 + m) * 1536 + h * 64 + off];
  }
  __syncthreads();

  bf16x8 aq[2][2];
#pragma unroll
  for (int kk = 0; kk < 2; ++kk)
#pragma unroll
    for (int i = 0; i < 2; ++i)
      aq[kk][i] = *(const bf16x8*)&Ps[(wave * 32 + i * 16 + l16) * LQ +
                                      kk * 32 + quad * 8];

  bf16x8 ones;
#pragma unroll
  for (int q = 0; q < 8; ++q) ones[q] = (__bf16)1.0f;

  f32x4 o[2][4] = {};
  f32x4 l_acc[2] = {};

  for (int t = 0; t < 32; ++t) {
    const int kv0 = t * 64;
#pragma unroll
    for (int it = 0; it < 2; ++it) {
      int c = tid + it * 256;
      int s = c >> 3, off = (c & 7) * 8;
      *(u16x8*)&Ks[s * LQ + off] =
          *(const u16x8*)&qkb[(long)(kv0 + s) * 1536 + 768 + h * 64 + off];
      *(u16x8*)&Vs[s * LQ + off] =  // s indexes d-rows of V^T
          *(const u16x8*)&vtb_h[s * 2048 + kv0 + off];
    }
    __syncthreads();

    // S^T = K @ Q^T : col=l16=qrow_local, row=quad*4+r=s_local
    f32x4 sc[4][2] = {};
#pragma unroll
    for (int kk = 0; kk < 2; ++kk) {
      bf16x8 bk[4];
#pragma unroll
      for (int j = 0; j < 4; ++j)
        bk[j] = *(const bf16x8*)&Ks[(j * 16 + l16) * LQ + kk * 32 + quad * 8];
#pragma unroll
      for (int j = 0; j < 4; ++j)
#pragma unroll
        for (int i = 0; i < 2; ++i)
          sc[j][i] = __builtin_amdgcn_mfma_f32_16x16x32_bf16(bk[j], aq[kk][i],
                                                             sc[j][i], 0, 0, 0);
    }

    // P[qrow][s] = exp2(S * 0.125*log2 e); packed b64 writes (wave-private)
#pragma unroll
    for (int i = 0; i < 2; ++i)
#pragma unroll
      for (int j = 0; j < 4; ++j) {
        f32x4 p;
#pragma unroll
        for (int r = 0; r < 4; ++r)
          p[r] = exp2f(sc[j][i][r] * 0.18033688011112042f);
        *(bf16x4*)&Ps[(wave * 32 + i * 16 + l16) * LQ + j * 16 + quad * 4] =
            __builtin_convertvector(p, bf16x4);
      }

    // O += P @ V ; l += 1 @ P
#pragma unroll
    for (int kk = 0; kk < 2; ++kk) {
      bf16x8 ap[2], bv[4];
#pragma unroll
      for (int i = 0; i < 2; ++i)
        ap[i] = *(const bf16x8*)&Ps[(wave * 32 + i * 16 + l16) * LQ + kk * 32 +
                                    quad * 8];
#pragma unroll
      for (int n = 0; n < 4; ++n)
        bv[n] = *(const bf16x8*)&Vs[(n * 16 + l16) * LQ + kk * 32 + quad * 8];
#pragma unroll
      for (int i = 0; i < 2; ++i) {
        l_acc[i] = __builtin_amdgcn_mfma_f32_16x16x32_bf16(ones, ap[i],
                                                           l_acc[i], 0, 0, 0);
#pragma unroll
        for (int n = 0; n < 4; ++n)
          o[i][n] = __builtin_amdgcn_mfma_f32_16x16x32_bf16(ap[i], bv[n],
                                                            o[i][n], 0, 0, 0);
      }
    }
    __syncthreads();
  }

  // epilogue: O/l -> attnb[2048][768]
#pragma unroll
  for (int i = 0; i < 2; ++i) {
    f32x4 inv;
#pragma unroll
    for (int r = 0; r < 4; ++r)
      inv[r] = 1.0f / __shfl(l_acc[i][0], quad * 4 + r, 64);
#pragma unroll
    for (int n = 0; n < 4; ++n)
#pragma unroll
      for (int r = 0; r < 4; ++r) {
        int srow = qt * 128 + wave * 32 + i * 16 + quad * 4 + r;
        ((__bf16*)attnb)[(long)srow * 768 + h * 64 + n * 16 + l16] =
            (__bf16)(o[i][n][r] * inv[r]);
      }
  }
}

extern "C" void kernel_launch(void* const* d_in, const int* in_sizes, int n_in,
                              void* d_out, int out_size, void* d_ws,
                              size_t ws_size, hipStream_t stream) {
  const float* x = (const float*)d_in[0];      // [4,2048,768] fp32
  const float* w_qkv = (const float*)d_in[1];  // [768,2304] fp32
  const float* w_out = (const float*)d_in[2];  // [768,768] fp32
  const float* b_out = (const float*)d_in[3];  // [768] fp32
  float* out = (float*)d_out;                  // [4,2048,768] fp32

  // ws layout (18.89 MB; proven budget >= 20.46 MB from prior rounds):
  //   wqkvT [2304][768] bf16   3,538,944
  //   woutT [768][768]  bf16   1,179,648
  //   xb    [2048][768] bf16   3,145,728   (per-batch, reused)
  //   qkb   [2048][1536] bf16  6,291,456   (Q cols 0..767, K cols 768..1535)
  //   vtb   [768][2048] bf16   3,145,728   (V^T, row = h*64+d)
  //   attnb [2048][768] bf16   3,145,728
  char* ws = (char*)d_ws;
  u16* wqkvT = (u16*)(ws);
  u16* woutT = (u16*)(ws + 3538944);
  u16* xb = (u16*)(ws + 4718592);
  u16* qkb = (u16*)(ws + 7864320);
  u16* vtb = (u16*)(ws + 14155776);
  u16* attnb = (u16*)(ws + 17301504);

  const size_t slice = (size_t)2048 * 768;

  prep_k<<<672, 256, 0, stream>>>(w_qkv, w_out, x, wqkvT, woutT, xb);
  for (int b = 0; b < 4; ++b) {
    int has_g2 = (b > 0) ? 1 : 0;
    combo_gemm<<<(has_g2 ? 96 : 0) + 288, 256, 0, stream>>>(
        attnb, out + (size_t)(b - 1) * slice * (b > 0 ? 1 : 0), b_out, xb,
        wqkvT, woutT, qkb, vtb, has_g2, 1);
    int has_cvt = (b < 3) ? 1 : 0;
    combo_attn<<<192 + (has_cvt ? 96 : 0), 256, 0, stream>>>(
        qkb, vtb, attnb, x + (size_t)(b + 1) * slice * (b < 3 ? 1 : 0), xb,
        has_cvt);
  }
  // final gemm2 for batch 3
  combo_gemm<<<96, 256, 0, stream>>>(attnb, out + 3 * slice, b_out, xb, wqkvT,
                                     woutT, qkb, vtb, 1, 0);
}

// Round 7
// 262.877 us; speedup vs baseline: 1.5199x; 1.5199x over previous
//
#include <hip/hip_runtime.h>
#include <stdint.h>

typedef unsigned short u16;
typedef __attribute__((ext_vector_type(8))) __bf16 bf16x8;
typedef __attribute__((ext_vector_type(4))) __bf16 bf16x4;
typedef __attribute__((ext_vector_type(8))) unsigned short u16x8;
typedef __attribute__((ext_vector_type(4))) float f32x4;

// async global->LDS, 16B/lane; LDS dest = wave-uniform base + lane*16.
__device__ __forceinline__ void glds16(const u16* g, u16* l) {
  auto* gp = reinterpret_cast<const __attribute__((address_space(1))) unsigned*>(
      reinterpret_cast<uintptr_t>(g));
  auto* lp = reinterpret_cast<__attribute__((address_space(3))) unsigned*>(
      reinterpret_cast<uintptr_t>(l));
  __builtin_amdgcn_global_load_lds(gp, lp, 16, 0, 0);
}

// ---------------- prep: weight transposes (fp32 -> bf16^T) ----------------
__device__ __forceinline__ void tp_tile(const float* __restrict__ src,
                                        u16* __restrict__ dst, int C, int Rd,
                                        int r0, int c0, u16* lds) {
  const int tid = threadIdx.x;
  {
    int r = tid >> 2, cb = (tid & 3) * 16;
#pragma unroll
    for (int k = 0; k < 4; ++k) {
      f32x4 v = *(const f32x4*)&src[(long)(r0 + r) * C + c0 + cb + k * 4];
      *(bf16x4*)&lds[r * 72 + cb + k * 4] = __builtin_convertvector(v, bf16x4);
    }
  }
  __syncthreads();
  {
    int c = tid >> 2, rb = (tid & 3) * 16;
    u16x8 o0, o1;
#pragma unroll
    for (int q = 0; q < 8; ++q) {
      o0[q] = lds[(rb + q) * 72 + c];
      o1[q] = lds[(rb + 8 + q) * 72 + c];
    }
    *(u16x8*)&dst[(long)(c0 + c) * Rd + r0 + rb] = o0;
    *(u16x8*)&dst[(long)(c0 + c) * Rd + r0 + rb + 8] = o1;
  }
}

// grid 576: [0,432) w_qkv tiles; [432,576) w_out tiles.
__global__ __launch_bounds__(256) void prep_k(const float* __restrict__ w_qkv,
                                              const float* __restrict__ w_out,
                                              u16* __restrict__ wqkvT,
                                              u16* __restrict__ woutT) {
  __shared__ u16 lds[64 * 72];
  int bx = blockIdx.x;
  if (bx < 432) {
    int tr = bx / 36, tc = bx % 36;
    tp_tile(w_qkv, wqkvT, 2304, 768, tr * 64, tc * 64, lds);
  } else {
    int t = bx - 432;
    tp_tile(w_out, woutT, 768, 768, (t / 12) * 64, (t % 12) * 64, lds);
  }
}

// ------- BT-GEMM: C[M][N] = A[M][K] @ BT[N][K]^T (+opt fp32 bias) -------
// bf16 operands staged via global_load_lds (unpadded [128][32]);
// fp32 operands staged via VGPR cvt (padded [128][40]).
template <bool A_F32, bool B_F32, bool OUT_F32>
__global__ __launch_bounds__(256) void gemm_k(const void* __restrict__ Av,
                                              const void* __restrict__ Bv,
                                              void* __restrict__ Cv,
                                              const float* __restrict__ bias,
                                              int N, int K) {
  __shared__ __align__(16) u16 As[128 * 40];
  __shared__ __align__(16) u16 Bs[128 * 40];
  constexpr int LA = A_F32 ? 40 : 32;
  constexpr int LB = B_F32 ? 40 : 32;

  const int tid = threadIdx.x;
  const int lane = tid & 63, wave = tid >> 6;
  const int quad = lane >> 4, l16 = lane & 15;
  const int wm = (wave >> 1) * 64, wn = (wave & 1) * 64;
  const int br = blockIdx.y * 128, bc = blockIdx.x * 128;

  f32x4 acc[4][4] = {};

  // glds addressing (bf16 operands)
  const int grow = wave * 32 + (lane >> 2);
  const int gcol = (lane & 3) * 8;
  const u16* ap0 = A_F32 ? nullptr : (const u16*)Av + (long)(br + grow) * K + gcol;
  const u16* bp0 = B_F32 ? nullptr : (const u16*)Bv + (long)(bc + grow) * K + gcol;
  u16* al0 = As + wave * 1024;
  u16* bl0 = Bs + wave * 1024;

  for (int k0 = 0; k0 < K; k0 += 32) {
    if (A_F32) {
      const float* A = (const float*)Av;
#pragma unroll
      for (int it = 0; it < 2; ++it) {
        int c = tid + it * 256;
        int m = c >> 2, off = (c & 3) * 8;
        f32x4 f0 = *(const f32x4*)&A[(long)(br + m) * K + k0 + off];
        f32x4 f1 = *(const f32x4*)&A[(long)(br + m) * K + k0 + off + 4];
        *(bf16x4*)&As[m * 40 + off] = __builtin_convertvector(f0, bf16x4);
        *(bf16x4*)&As[m * 40 + off + 4] = __builtin_convertvector(f1, bf16x4);
      }
    } else {
      glds16(ap0 + k0, al0);
      glds16(ap0 + k0 + 16 * K, al0 + 512);
    }
    if (B_F32) {
      const float* B = (const float*)Bv;
#pragma unroll
      for (int it = 0; it < 2; ++it) {
        int c = tid + it * 256;
        int m = c >> 2, off = (c & 3) * 8;
        f32x4 f0 = *(const f32x4*)&B[(long)(bc + m) * K + k0 + off];
        f32x4 f1 = *(const f32x4*)&B[(long)(bc + m) * K + k0 + off + 4];
        *(bf16x4*)&Bs[m * 40 + off] = __builtin_convertvector(f0, bf16x4);
        *(bf16x4*)&Bs[m * 40 + off + 4] = __builtin_convertvector(f1, bf16x4);
      }
    } else {
      glds16(bp0 + k0, bl0);
      glds16(bp0 + k0 + 16 * K, bl0 + 512);
    }
    __syncthreads();  // drains vmcnt (glds) + lgkm before LDS reads
    bf16x8 af[4], bf[4];
#pragma unroll
    for (int i = 0; i < 4; ++i)
      af[i] = *(const bf16x8*)&As[(wm + i * 16 + l16) * LA + quad * 8];
#pragma unroll
    for (int j = 0; j < 4; ++j)
      bf[j] = *(const bf16x8*)&Bs[(wn + j * 16 + l16) * LB + quad * 8];
#pragma unroll
    for (int i = 0; i < 4; ++i)
#pragma unroll
      for (int j = 0; j < 4; ++j)
        acc[i][j] = __builtin_amdgcn_mfma_f32_16x16x32_bf16(af[i], bf[j],
                                                            acc[i][j], 0, 0, 0);
    __syncthreads();
  }

#pragma unroll
  for (int i = 0; i < 4; ++i)
#pragma unroll
    for (int j = 0; j < 4; ++j)
#pragma unroll
      for (int r = 0; r < 4; ++r) {
        int row = br + wm + i * 16 + quad * 4 + r;
        int col = bc + wn + j * 16 + l16;
        float v = acc[i][j][r];
        if (OUT_F32) {
          ((float*)Cv)[(long)row * N + col] = v + bias[col];
        } else {
          ((__bf16*)Cv)[(long)row * N + col] = (__bf16)v;
        }
      }
}

// ---------------- fused flash attention (round-5 math, new strides) --------
// qk: [*][1536] bf16 rows b*2048+s (Q cols 0..767, K cols 768..1535), base
//     pre-offset to the batch group. vt: [768][8192] bf16, cols pre-offset.
// attnb: [BG*2048][768] bf16. grid (16, BG*12).
__global__ __launch_bounds__(256, 4) void attn_k(const u16* __restrict__ qk,
                                                 const u16* __restrict__ vt,
                                                 u16* __restrict__ attnb) {
  const int LQ = 72;
  __shared__ __align__(16) u16 Ks[64 * LQ];
  __shared__ __align__(16) u16 Vs[64 * LQ];
  __shared__ __align__(16) u16 Ps[128 * LQ];

  const int tid = threadIdx.x;
  const int lane = tid & 63, wave = tid >> 6;
  const int quad = lane >> 4, l16 = lane & 15;
  const int qt = blockIdx.x;
  const int bloc = blockIdx.y / 12, h = blockIdx.y % 12;
  const long rowbase = (long)bloc * 2048;

  // stage Q tile into Ps
#pragma unroll
  for (int it = 0; it < 4; ++it) {
    int c = tid + it * 256;
    int m = c >> 3, off = (c & 7) * 8;
    *(u16x8*)&Ps[m * LQ + off] =
        *(const u16x8*)&qk[(rowbase + qt * 128 + m) * 1536 + h * 64 + off];
  }
  __syncthreads();

  bf16x8 aq[2][2];
#pragma unroll
  for (int kk = 0; kk < 2; ++kk)
#pragma unroll
    for (int i = 0; i < 2; ++i)
      aq[kk][i] = *(const bf16x8*)&Ps[(wave * 32 + i * 16 + l16) * LQ +
                                      kk * 32 + quad * 8];

  bf16x8 ones;
#pragma unroll
  for (int q = 0; q < 8; ++q) ones[q] = (__bf16)1.0f;

  f32x4 o[2][4] = {};
  f32x4 l_acc[2] = {};

  for (int t = 0; t < 32; ++t) {
    const int kv0 = t * 64;
#pragma unroll
    for (int it = 0; it < 2; ++it) {
      int c = tid + it * 256;
      int s = c >> 3, off = (c & 7) * 8;
      *(u16x8*)&Ks[s * LQ + off] =
          *(const u16x8*)&qk[(rowbase + kv0 + s) * 1536 + 768 + h * 64 + off];
      *(u16x8*)&Vs[s * LQ + off] =  // s indexes d-rows of V^T
          *(const u16x8*)&vt[(long)(h * 64 + s) * 8192 + rowbase + kv0 + off];
    }
    __syncthreads();

    // S^T = K @ Q^T : col=l16=qrow_local, row=quad*4+r=s_local
    f32x4 sc[4][2] = {};
#pragma unroll
    for (int kk = 0; kk < 2; ++kk) {
      bf16x8 bk[4];
#pragma unroll
      for (int j = 0; j < 4; ++j)
        bk[j] = *(const bf16x8*)&Ks[(j * 16 + l16) * LQ + kk * 32 + quad * 8];
#pragma unroll
      for (int j = 0; j < 4; ++j)
#pragma unroll
        for (int i = 0; i < 2; ++i)
          sc[j][i] = __builtin_amdgcn_mfma_f32_16x16x32_bf16(bk[j], aq[kk][i],
                                                             sc[j][i], 0, 0, 0);
    }

    // P[qrow][s] = exp2(S * 0.125*log2 e); packed b64 writes (wave-private)
#pragma unroll
    for (int i = 0; i < 2; ++i)
#pragma unroll
      for (int j = 0; j < 4; ++j) {
        f32x4 p;
#pragma unroll
        for (int r = 0; r < 4; ++r)
          p[r] = exp2f(sc[j][i][r] * 0.18033688011112042f);
        *(bf16x4*)&Ps[(wave * 32 + i * 16 + l16) * LQ + j * 16 + quad * 4] =
            __builtin_convertvector(p, bf16x4);
      }

    // O += P @ V ; l += 1 @ P
#pragma unroll
    for (int kk = 0; kk < 2; ++kk) {
      bf16x8 ap[2], bv[4];
#pragma unroll
      for (int i = 0; i < 2; ++i)
        ap[i] = *(const bf16x8*)&Ps[(wave * 32 + i * 16 + l16) * LQ + kk * 32 +
                                    quad * 8];
#pragma unroll
      for (int n = 0; n < 4; ++n)
        bv[n] = *(const bf16x8*)&Vs[(n * 16 + l16) * LQ + kk * 32 + quad * 8];
#pragma unroll
      for (int i = 0; i < 2; ++i) {
        l_acc[i] = __builtin_amdgcn_mfma_f32_16x16x32_bf16(ones, ap[i],
                                                           l_acc[i], 0, 0, 0);
#pragma unroll
        for (int n = 0; n < 4; ++n)
          o[i][n] = __builtin_amdgcn_mfma_f32_16x16x32_bf16(ap[i], bv[n],
                                                            o[i][n], 0, 0, 0);
      }
    }
    __syncthreads();
  }

  // epilogue: O/l -> attnb
#pragma unroll
  for (int i = 0; i < 2; ++i) {
    f32x4 inv;
#pragma unroll
    for (int r = 0; r < 4; ++r)
      inv[r] = 1.0f / __shfl(l_acc[i][0], quad * 4 + r, 64);
#pragma unroll
    for (int n = 0; n < 4; ++n)
#pragma unroll
      for (int r = 0; r < 4; ++r) {
        int srow = qt * 128 + wave * 32 + i * 16 + quad * 4 + r;
        ((__bf16*)attnb)[(rowbase + srow) * 768 + h * 64 + n * 16 + l16] =
            (__bf16)(o[i][n][r] * inv[r]);
      }
  }
}

extern "C" void kernel_launch(void* const* d_in, const int* in_sizes, int n_in,
                              void* d_out, int out_size, void* d_ws,
                              size_t ws_size, hipStream_t stream) {
  const float* x = (const float*)d_in[0];      // [4,2048,768] fp32
  const float* w_qkv = (const float*)d_in[1];  // [768,2304] fp32
  const float* w_out = (const float*)d_in[2];  // [768,768] fp32
  const float* b_out = (const float*)d_in[3];  // [768] fp32
  float* out = (float*)d_out;                  // [4,2048,768] fp32

  // ws: wqkvT [2304][768] 3,538,944 | woutT [768][768] 1,179,648
  //     vt [768][8192] 12,582,912   | attnb [BG*2048][768] BG*3,145,728
  // qk (Q,K all batches) [8192][1536] bf16 = 25,165,824 B lives in d_out;
  // gemm2(b) overwrites only batch-b rows after attn(b) has consumed them.
  char* ws = (char*)d_ws;
  u16* wqkvT = (u16*)(ws);
  u16* woutT = (u16*)(ws + 3538944);
  u16* vt = (u16*)(ws + 4718592);
  u16* attnb = (u16*)(ws + 17301504);
  u16* qkb = (u16*)d_out;

  int BG = 1;
  if (ws_size >= 17301504 + 4 * 3145728) BG = 4;
  else if (ws_size >= 17301504 + 2 * 3145728) BG = 2;

  prep_k<<<576, 256, 0, stream>>>(w_qkv, w_out, wqkvT, woutT);
  // qk[8192][1536] = x @ wqkvT[0:1536]^T  (fp32 A, glds B)
  gemm_k<true, false, false><<<dim3(12, 64), 256, 0, stream>>>(
      x, wqkvT, qkb, nullptr, 1536, 768);
  // vt[768][8192] = wvT @ x^T  (glds A, fp32 B)
  gemm_k<false, true, false><<<dim3(64, 6), 256, 0, stream>>>(
      wqkvT + 1536 * 768, x, vt, nullptr, 8192, 768);

  for (int bb = 0; bb < 4; bb += BG) {
    attn_k<<<dim3(16, BG * 12), 256, 0, stream>>>(
        qkb + (size_t)bb * 2048 * 1536, vt + (size_t)bb * 2048, attnb);
    gemm_k<false, false, true><<<dim3(6, BG * 16), 256, 0, stream>>>(
        attnb, woutT, out + (size_t)bb * 2048 * 768, b_out, 768, 768);
  }
}

// Round 8
// 256.063 us; speedup vs baseline: 1.5603x; 1.0266x over previous
//
#include <hip/hip_runtime.h>
#include <stdint.h>

typedef unsigned short u16;
typedef __attribute__((ext_vector_type(8))) __bf16 bf16x8;
typedef __attribute__((ext_vector_type(4))) __bf16 bf16x4;
typedef __attribute__((ext_vector_type(8))) unsigned short u16x8;
typedef __attribute__((ext_vector_type(4))) float f32x4;

// async global->LDS, 16B/lane; LDS dest = wave-uniform base + lane*16.
__device__ __forceinline__ void glds16(const u16* g, u16* l) {
  auto* gp = reinterpret_cast<const __attribute__((address_space(1))) unsigned*>(
      reinterpret_cast<uintptr_t>(g));
  auto* lp = reinterpret_cast<__attribute__((address_space(3))) unsigned*>(
      reinterpret_cast<uintptr_t>(l));
  __builtin_amdgcn_global_load_lds(gp, lp, 16, 0, 0);
}

// ---------------- prep: weight transposes (fp32 -> bf16^T) ----------------
__device__ __forceinline__ void tp_tile(const float* __restrict__ src,
                                        u16* __restrict__ dst, int C, int Rd,
                                        int r0, int c0, u16* lds) {
  const int tid = threadIdx.x;
  {
    int r = tid >> 2, cb = (tid & 3) * 16;
#pragma unroll
    for (int k = 0; k < 4; ++k) {
      f32x4 v = *(const f32x4*)&src[(long)(r0 + r) * C + c0 + cb + k * 4];
      *(bf16x4*)&lds[r * 72 + cb + k * 4] = __builtin_convertvector(v, bf16x4);
    }
  }
  __syncthreads();
  {
    int c = tid >> 2, rb = (tid & 3) * 16;
    u16x8 o0, o1;
#pragma unroll
    for (int q = 0; q < 8; ++q) {
      o0[q] = lds[(rb + q) * 72 + c];
      o1[q] = lds[(rb + 8 + q) * 72 + c];
    }
    *(u16x8*)&dst[(long)(c0 + c) * Rd + r0 + rb] = o0;
    *(u16x8*)&dst[(long)(c0 + c) * Rd + r0 + rb + 8] = o1;
  }
}

__global__ __launch_bounds__(256) void prep_k(const float* __restrict__ w_qkv,
                                              const float* __restrict__ w_out,
                                              u16* __restrict__ wqkvT,
                                              u16* __restrict__ woutT) {
  __shared__ u16 lds[64 * 72];
  int bx = blockIdx.x;
  if (bx < 432) {
    int tr = bx / 36, tc = bx % 36;
    tp_tile(w_qkv, wqkvT, 2304, 768, tr * 64, tc * 64, lds);
  } else {
    int t = bx - 432;
    tp_tile(w_out, woutT, 768, 768, (t / 12) * 64, (t % 12) * 64, lds);
  }
}

// ------- BT-GEMM core: C[M][N] = A[M][K] @ BT[N][K]^T (+opt fp32 bias) -----
// bf16 operands: glds16 staging into XOR-swizzled [128][32] (chunk c of row r
// stored at phys chunk c^((r>>1)&3) -> conflict-free frag reads).
// fp32 operands: VGPR cvt staging into padded [128][40].
template <bool AF32, bool BF32, bool OF32>
__device__ __forceinline__ void gemm_core(const void* __restrict__ Av,
                                          const void* __restrict__ Bv,
                                          void* __restrict__ Cv,
                                          const float* __restrict__ bias,
                                          int N, int K, int br, int bc,
                                          u16* As, u16* Bs) {
  constexpr int LA = AF32 ? 40 : 32;
  constexpr int LB = BF32 ? 40 : 32;
  const int tid = threadIdx.x;
  const int lane = tid & 63, wave = tid >> 6;
  const int quad = lane >> 4, l16 = lane & 15;
  const int wm = (wave >> 1) * 64, wn = (wave & 1) * 64;

  f32x4 acc[4][4] = {};

  // glds addressing: lane l -> row wave*32+(l>>2), logical chunk (l&3)^((l>>3)&3)
  const int srow = wave * 32 + (lane >> 2);
  const int scol = ((lane & 3) ^ ((lane >> 3) & 3)) * 8;
  const u16* ag = AF32 ? nullptr : (const u16*)Av + (long)(br + srow) * K + scol;
  const u16* bg = BF32 ? nullptr : (const u16*)Bv + (long)(bc + srow) * K + scol;
  // swizzled frag-read chunk offsets (u16)
  const int rda = AF32 ? quad * 8 : ((quad ^ ((l16 >> 1) & 3)) * 8);
  const int rdb = BF32 ? quad * 8 : ((quad ^ ((l16 >> 1) & 3)) * 8);

  for (int k0 = 0; k0 < K; k0 += 32) {
    if (AF32) {
      const float* A = (const float*)Av;
#pragma unroll
      for (int it = 0; it < 2; ++it) {
        int c = tid + it * 256;
        int m = c >> 2, off = (c & 3) * 8;
        f32x4 f0 = *(const f32x4*)&A[(long)(br + m) * K + k0 + off];
        f32x4 f1 = *(const f32x4*)&A[(long)(br + m) * K + k0 + off + 4];
        *(bf16x4*)&As[m * 40 + off] = __builtin_convertvector(f0, bf16x4);
        *(bf16x4*)&As[m * 40 + off + 4] = __builtin_convertvector(f1, bf16x4);
      }
    } else {
      glds16(ag + k0, As + wave * 1024);
      glds16(ag + k0 + 16 * K, As + wave * 1024 + 512);
    }
    if (BF32) {
      const float* B = (const float*)Bv;
#pragma unroll
      for (int it = 0; it < 2; ++it) {
        int c = tid + it * 256;
        int m = c >> 2, off = (c & 3) * 8;
        f32x4 f0 = *(const f32x4*)&B[(long)(bc + m) * K + k0 + off];
        f32x4 f1 = *(const f32x4*)&B[(long)(bc + m) * K + k0 + off + 4];
        *(bf16x4*)&Bs[m * 40 + off] = __builtin_convertvector(f0, bf16x4);
        *(bf16x4*)&Bs[m * 40 + off + 4] = __builtin_convertvector(f1, bf16x4);
      }
    } else {
      glds16(bg + k0, Bs + wave * 1024);
      glds16(bg + k0 + 16 * K, Bs + wave * 1024 + 512);
    }
    __syncthreads();
    bf16x8 af[4], bf[4];
#pragma unroll
    for (int i = 0; i < 4; ++i)
      af[i] = *(const bf16x8*)&As[(wm + i * 16 + l16) * LA + rda];
#pragma unroll
    for (int j = 0; j < 4; ++j)
      bf[j] = *(const bf16x8*)&Bs[(wn + j * 16 + l16) * LB + rdb];
#pragma unroll
    for (int i = 0; i < 4; ++i)
#pragma unroll
      for (int j = 0; j < 4; ++j)
        acc[i][j] = __builtin_amdgcn_mfma_f32_16x16x32_bf16(af[i], bf[j],
                                                            acc[i][j], 0, 0, 0);
    __syncthreads();
  }

#pragma unroll
  for (int i = 0; i < 4; ++i)
#pragma unroll
    for (int j = 0; j < 4; ++j)
#pragma unroll
      for (int r = 0; r < 4; ++r) {
        int row = br + wm + i * 16 + quad * 4 + r;
        int col = bc + wn + j * 16 + l16;
        float v = acc[i][j][r];
        if (OF32) {
          ((float*)Cv)[(long)row * N + col] = v + bias[col];
        } else {
          ((__bf16*)Cv)[(long)row * N + col] = (__bf16)v;
        }
      }
}

// ---- fused launch: qk gemm (768 blocks) + vt gemm (384 blocks) ----
// qk[8192][1536] = x @ wqkvT[0:1536]^T ; vt[768][8192] = wvT @ x^T
__global__ __launch_bounds__(256) void qkvt_k(const float* __restrict__ x,
                                              const u16* __restrict__ wqkvT,
                                              u16* __restrict__ qk,
                                              u16* __restrict__ vt) {
  __shared__ __align__(16) u16 As[128 * 40];
  __shared__ __align__(16) u16 Bs[128 * 40];
  int bx = blockIdx.x;
  if (bx < 768) {
    gemm_core<true, false, false>(x, wqkvT, qk, nullptr, 1536, 768,
                                  (bx / 12) * 128, (bx % 12) * 128, As, Bs);
  } else {
    int i = bx - 768;  // 6 row-tiles x 64 col-tiles
    gemm_core<false, true, false>(wqkvT + 1536 * 768, x, vt, nullptr, 8192, 768,
                                  (i >> 6) * 128, (i & 63) * 128, As, Bs);
  }
}

// ---- gemm2: out[8192][768] = attnb @ woutT + bias (fp32 out) ----
__global__ __launch_bounds__(256) void gemm2_k(const u16* __restrict__ attnb,
                                               const u16* __restrict__ woutT,
                                               float* __restrict__ out,
                                               const float* __restrict__ bias) {
  __shared__ __align__(16) u16 As[128 * 40];
  __shared__ __align__(16) u16 Bs[128 * 40];
  gemm_core<false, false, true>(attnb, woutT, out, bias, 768, 768,
                                blockIdx.y * 128, blockIdx.x * 128, As, Bs);
}

// ---------------- fused flash attention (glds K/V, swizzled tiles) ---------
// qk: [8192][1536] bf16 (Q cols 0..767, K cols 768..1535); vt: [768][8192].
// grid (16, 48). Q-tile 128, KV-tile 64. Ks/Vs are [64][64] XOR-swizzled
// (chunk c of row r at phys c^(r&7)); Ps padded [128][72] (Q staging + P).
__global__ __launch_bounds__(256, 4) void attn_k(const u16* __restrict__ qk,
                                                 const u16* __restrict__ vt,
                                                 u16* __restrict__ attnb) {
  const int LQ = 72;
  __shared__ __align__(16) u16 Ks[64 * 64];
  __shared__ __align__(16) u16 Vs[64 * 64];
  __shared__ __align__(16) u16 Ps[128 * LQ];

  const int tid = threadIdx.x;
  const int lane = tid & 63, wave = tid >> 6;
  const int quad = lane >> 4, l16 = lane & 15;
  const int qt = blockIdx.x;
  const int bloc = blockIdx.y / 12, h = blockIdx.y % 12;
  const long rowbase = (long)bloc * 2048;

  // stage Q tile into Ps (one-time; vectorized VGPR path, padded)
#pragma unroll
  for (int it = 0; it < 4; ++it) {
    int c = tid + it * 256;
    int m = c >> 3, off = (c & 7) * 8;
    *(u16x8*)&Ps[m * LQ + off] =
        *(const u16x8*)&qk[(rowbase + qt * 128 + m) * 1536 + h * 64 + off];
  }
  __syncthreads();

  bf16x8 aq[2][2];
#pragma unroll
  for (int kk = 0; kk < 2; ++kk)
#pragma unroll
    for (int i = 0; i < 2; ++i)
      aq[kk][i] = *(const bf16x8*)&Ps[(wave * 32 + i * 16 + l16) * LQ +
                                      kk * 32 + quad * 8];

  bf16x8 ones;
#pragma unroll
  for (int q = 0; q < 8; ++q) ones[q] = (__bf16)1.0f;

  // glds staging addresses: lane l -> tile row wave*16+(l>>3), logical chunk
  // ((l&7)^(l>>3)), phys chunk l&7. Second glds covers rows +8.
  const int trow = lane >> 3;
  const int tcol = ((lane & 7) ^ trow) * 8;
  const u16* kg = qk + (rowbase + wave * 16 + trow) * 1536 + 768 + h * 64 + tcol;
  const u16* vg = vt + (long)(h * 64 + wave * 16 + trow) * 8192 + rowbase + tcol;
  u16* kl = Ks + wave * 1024;
  u16* vl = Vs + wave * 1024;
  // swizzled frag-read chunk offset base (u16): phys = (kk*4+quad) ^ (l16&7)
  const int sw = l16 & 7;

  f32x4 o[2][4] = {};
  f32x4 l_acc[2] = {};

  for (int t = 0; t < 32; ++t) {
    const long kvK = (long)t * 64 * 1536;  // K advances by rows
    const long kvV = (long)t * 64;         // V^T advances by cols
    glds16(kg + kvK, kl);
    glds16(kg + kvK + 8 * 1536, kl + 512);
    glds16(vg + kvV, vl);
    glds16(vg + kvV + 8 * 8192, vl + 512);
    __syncthreads();

    // S^T = K @ Q^T : col=l16=qrow_local, row=quad*4+r=s_local
    f32x4 sc[4][2] = {};
#pragma unroll
    for (int kk = 0; kk < 2; ++kk) {
      bf16x8 bk[4];
#pragma unroll
      for (int j = 0; j < 4; ++j)
        bk[j] = *(const bf16x8*)&Ks[(j * 16 + l16) * 64 +
                                    ((kk * 4 + quad) ^ sw) * 8];
#pragma unroll
      for (int j = 0; j < 4; ++j)
#pragma unroll
        for (int i = 0; i < 2; ++i)
          sc[j][i] = __builtin_amdgcn_mfma_f32_16x16x32_bf16(bk[j], aq[kk][i],
                                                             sc[j][i], 0, 0, 0);
    }

    // P[qrow][s] = exp2(S * 0.125*log2 e); packed b64 writes (wave-private)
#pragma unroll
    for (int i = 0; i < 2; ++i)
#pragma unroll
      for (int j = 0; j < 4; ++j) {
        f32x4 p;
#pragma unroll
        for (int r = 0; r < 4; ++r)
          p[r] = exp2f(sc[j][i][r] * 0.18033688011112042f);
        *(bf16x4*)&Ps[(wave * 32 + i * 16 + l16) * LQ + j * 16 + quad * 4] =
            __builtin_convertvector(p, bf16x4);
      }

    // O += P @ V ; l += 1 @ P
#pragma unroll
    for (int kk = 0; kk < 2; ++kk) {
      bf16x8 ap[2], bv[4];
#pragma unroll
      for (int i = 0; i < 2; ++i)
        ap[i] = *(const bf16x8*)&Ps[(wave * 32 + i * 16 + l16) * LQ + kk * 32 +
                                    quad * 8];
#pragma unroll
      for (int n = 0; n < 4; ++n)
        bv[n] = *(const bf16x8*)&Vs[(n * 16 + l16) * 64 +
                                    ((kk * 4 + quad) ^ sw) * 8];
#pragma unroll
      for (int i = 0; i < 2; ++i) {
        l_acc[i] = __builtin_amdgcn_mfma_f32_16x16x32_bf16(ones, ap[i],
                                                           l_acc[i], 0, 0, 0);
#pragma unroll
        for (int n = 0; n < 4; ++n)
          o[i][n] = __builtin_amdgcn_mfma_f32_16x16x32_bf16(ap[i], bv[n],
                                                            o[i][n], 0, 0, 0);
      }
    }
    __syncthreads();
  }

  // epilogue: O/l -> attnb[8192][768]
#pragma unroll
  for (int i = 0; i < 2; ++i) {
    f32x4 inv;
#pragma unroll
    for (int r = 0; r < 4; ++r)
      inv[r] = 1.0f / __shfl(l_acc[i][0], quad * 4 + r, 64);
#pragma unroll
    for (int n = 0; n < 4; ++n)
#pragma unroll
      for (int r = 0; r < 4; ++r) {
        int srow = qt * 128 + wave * 32 + i * 16 + quad * 4 + r;
        ((__bf16*)attnb)[(rowbase + srow) * 768 + h * 64 + n * 16 + l16] =
            (__bf16)(o[i][n][r] * inv[r]);
      }
  }
}

extern "C" void kernel_launch(void* const* d_in, const int* in_sizes, int n_in,
                              void* d_out, int out_size, void* d_ws,
                              size_t ws_size, hipStream_t stream) {
  const float* x = (const float*)d_in[0];      // [4,2048,768] fp32
  const float* w_qkv = (const float*)d_in[1];  // [768,2304] fp32
  const float* w_out = (const float*)d_in[2];  // [768,768] fp32
  const float* b_out = (const float*)d_in[3];  // [768] fp32
  float* out = (float*)d_out;                  // [4,2048,768] fp32

  // ws (29,884,416 B total — proven available by round 7's BG=4 pass):
  //   wqkvT [2304][768] bf16   3,538,944
  //   woutT [768][768]  bf16   1,179,648
  //   vt    [768][8192] bf16  12,582,912
  //   attnb [8192][768] bf16  12,582,912
  // qk [8192][1536] bf16 (25,165,824 B) lives in d_out until gemm2 overwrites.
  char* ws = (char*)d_ws;
  u16* wqkvT = (u16*)(ws);
  u16* woutT = (u16*)(ws + 3538944);
  u16* vt = (u16*)(ws + 4718592);
  u16* attnb = (u16*)(ws + 17301504);
  u16* qkb = (u16*)d_out;

  prep_k<<<576, 256, 0, stream>>>(w_qkv, w_out, wqkvT, woutT);
  qkvt_k<<<1152, 256, 0, stream>>>(x, wqkvT, qkb, vt);
  attn_k<<<dim3(16, 48), 256, 0, stream>>>(qkb, vt, attnb);
  gemm2_k<<<dim3(6, 64), 256, 0, stream>>>(attnb, woutT, out, b_out);
}

// Round 9
// 238.409 us; speedup vs baseline: 1.6759x; 1.0740x over previous
//
#include <hip/hip_runtime.h>
#include <stdint.h>

typedef unsigned short u16;
typedef __attribute__((ext_vector_type(8))) __bf16 bf16x8;
typedef __attribute__((ext_vector_type(4))) __bf16 bf16x4;
typedef __attribute__((ext_vector_type(8))) unsigned short u16x8;
typedef __attribute__((ext_vector_type(4))) float f32x4;

// async global->LDS, 16B/lane; LDS dest = wave-uniform base + lane*16.
__device__ __forceinline__ void glds16(const u16* g, u16* l) {
  auto* gp = reinterpret_cast<const __attribute__((address_space(1))) unsigned*>(
      reinterpret_cast<uintptr_t>(g));
  auto* lp = reinterpret_cast<__attribute__((address_space(3))) unsigned*>(
      reinterpret_cast<uintptr_t>(l));
  __builtin_amdgcn_global_load_lds(gp, lp, 16, 0, 0);
}

// ---------------- prep: weight transposes + x cvt (fp32 -> bf16) ----------
__device__ __forceinline__ void tp_tile(const float* __restrict__ src,
                                        u16* __restrict__ dst, int C, int Rd,
                                        int r0, int c0, u16* lds) {
  const int tid = threadIdx.x;
  {
    int r = tid >> 2, cb = (tid & 3) * 16;
#pragma unroll
    for (int k = 0; k < 4; ++k) {
      f32x4 v = *(const f32x4*)&src[(long)(r0 + r) * C + c0 + cb + k * 4];
      *(bf16x4*)&lds[r * 72 + cb + k * 4] = __builtin_convertvector(v, bf16x4);
    }
  }
  __syncthreads();
  {
    int c = tid >> 2, rb = (tid & 3) * 16;
    u16x8 o0, o1;
#pragma unroll
    for (int q = 0; q < 8; ++q) {
      o0[q] = lds[(rb + q) * 72 + c];
      o1[q] = lds[(rb + 8 + q) * 72 + c];
    }
    *(u16x8*)&dst[(long)(c0 + c) * Rd + r0 + rb] = o0;
    *(u16x8*)&dst[(long)(c0 + c) * Rd + r0 + rb + 8] = o1;
  }
}

// grid 768: [0,432) w_qkv tiles; [432,576) w_out tiles; [576,768) x cvt.
__global__ __launch_bounds__(256) void prep_k(const float* __restrict__ w_qkv,
                                              const float* __restrict__ w_out,
                                              const float* __restrict__ x,
                                              u16* __restrict__ wqkvT,
                                              u16* __restrict__ woutT,
                                              u16* __restrict__ xb) {
  __shared__ u16 lds[64 * 72];
  int bx = blockIdx.x;
  if (bx < 432) {
    int tr = bx / 36, tc = bx % 36;
    tp_tile(w_qkv, wqkvT, 2304, 768, tr * 64, tc * 64, lds);
  } else if (bx < 576) {
    int t = bx - 432;
    tp_tile(w_out, woutT, 768, 768, (t / 12) * 64, (t % 12) * 64, lds);
  } else {
    // cvt x [8192][768] fp32 -> xb bf16: 6,291,456 elems,
    // 192 blocks * 256 thr * 8 elems * 16 iters
    int base = ((bx - 576) * 256 + (int)threadIdx.x) * 8;
#pragma unroll
    for (int it = 0; it < 16; ++it, base += 393216) {
      f32x4 a = *(const f32x4*)&x[base];
      f32x4 b = *(const f32x4*)&x[base + 4];
      *(bf16x4*)&xb[base] = __builtin_convertvector(a, bf16x4);
      *(bf16x4*)&xb[base + 4] = __builtin_convertvector(b, bf16x4);
    }
  }
}

// ------- BT-GEMM core (all-bf16): C = A[M][K] @ BT[N][K]^T (+opt bias) -----
// glds16 staging into XOR-swizzled [128][32]: chunk c of row r stored at
// phys chunk c^((r>>1)&3) -> conflict-free frag reads.
template <bool OF32>
__device__ __forceinline__ void gemm_core(const u16* __restrict__ A,
                                          const u16* __restrict__ BT,
                                          void* __restrict__ Cv,
                                          const float* __restrict__ bias,
                                          int N, int K, int br, int bc,
                                          u16* As, u16* Bs) {
  const int tid = threadIdx.x;
  const int lane = tid & 63, wave = tid >> 6;
  const int quad = lane >> 4, l16 = lane & 15;
  const int wm = (wave >> 1) * 64, wn = (wave & 1) * 64;

  f32x4 acc[4][4] = {};

  // glds: lane l -> row wave*32+(l>>2), logical chunk (l&3)^((l>>3)&3)
  const int srow = wave * 32 + (lane >> 2);
  const int scol = ((lane & 3) ^ ((lane >> 3) & 3)) * 8;
  const u16* ag = A + (long)(br + srow) * K + scol;
  const u16* bg = BT + (long)(bc + srow) * K + scol;
  const int rd = (quad ^ ((l16 >> 1) & 3)) * 8;

  for (int k0 = 0; k0 < K; k0 += 32) {
    glds16(ag + k0, As + wave * 1024);
    glds16(ag + k0 + 16 * K, As + wave * 1024 + 512);
    glds16(bg + k0, Bs + wave * 1024);
    glds16(bg + k0 + 16 * K, Bs + wave * 1024 + 512);
    __syncthreads();
    bf16x8 af[4], bf[4];
#pragma unroll
    for (int i = 0; i < 4; ++i)
      af[i] = *(const bf16x8*)&As[(wm + i * 16 + l16) * 32 + rd];
#pragma unroll
    for (int j = 0; j < 4; ++j)
      bf[j] = *(const bf16x8*)&Bs[(wn + j * 16 + l16) * 32 + rd];
#pragma unroll
    for (int i = 0; i < 4; ++i)
#pragma unroll
      for (int j = 0; j < 4; ++j)
        acc[i][j] = __builtin_amdgcn_mfma_f32_16x16x32_bf16(af[i], bf[j],
                                                            acc[i][j], 0, 0, 0);
    __syncthreads();
  }

#pragma unroll
  for (int i = 0; i < 4; ++i)
#pragma unroll
    for (int j = 0; j < 4; ++j)
#pragma unroll
      for (int r = 0; r < 4; ++r) {
        int row = br + wm + i * 16 + quad * 4 + r;
        int col = bc + wn + j * 16 + l16;
        float v = acc[i][j][r];
        if (OF32) {
          ((float*)Cv)[(long)row * N + col] = v + bias[col];
        } else {
          ((__bf16*)Cv)[(long)row * N + col] = (__bf16)v;
        }
      }
}

// ---- fused: qk gemm (768 blocks) + vt gemm (384 blocks), all bf16 ----
__global__ __launch_bounds__(256) void qkvt_k(const u16* __restrict__ xb,
                                              const u16* __restrict__ wqkvT,
                                              u16* __restrict__ qk,
                                              u16* __restrict__ vt) {
  __shared__ __align__(16) u16 As[128 * 32];
  __shared__ __align__(16) u16 Bs[128 * 32];
  int bx = blockIdx.x;
  if (bx < 768) {
    gemm_core<false>(xb, wqkvT, qk, nullptr, 1536, 768, (bx / 12) * 128,
                     (bx % 12) * 128, As, Bs);
  } else {
    int i = bx - 768;  // 6 row-tiles x 64 col-tiles
    gemm_core<false>(wqkvT + 1536 * 768, xb, vt, nullptr, 8192, 768,
                     (i >> 6) * 128, (i & 63) * 128, As, Bs);
  }
}

// ---- gemm2: out[8192][768] = attnb @ woutT + bias (fp32 out) ----
__global__ __launch_bounds__(256) void gemm2_k(const u16* __restrict__ attnb,
                                               const u16* __restrict__ woutT,
                                               float* __restrict__ out,
                                               const float* __restrict__ bias) {
  __shared__ __align__(16) u16 As[128 * 32];
  __shared__ __align__(16) u16 Bs[128 * 32];
  gemm_core<true>(attnb, woutT, out, bias, 768, 768, blockIdx.y * 128,
                  blockIdx.x * 128, As, Bs);
}

// ---------------- fused flash attention (XCD-swizzled grid) ----------------
// grid 768 (1D). xcd=bid&7, slot=bid>>3, bh=xcd*6+(slot>>4), qt=slot&15:
// all 16 q-tiles of one head co-locate on one XCD (K/V L2 reuse).
__global__ __launch_bounds__(256, 4) void attn_k(const u16* __restrict__ qk,
                                                 const u16* __restrict__ vt,
                                                 u16* __restrict__ attnb) {
  const int LQ = 72;
  __shared__ __align__(16) u16 Ks[64 * 64];
  __shared__ __align__(16) u16 Vs[64 * 64];
  __shared__ __align__(16) u16 Ps[128 * LQ];

  const int tid = threadIdx.x;
  const int lane = tid & 63, wave = tid >> 6;
  const int quad = lane >> 4, l16 = lane & 15;
  const int bid = blockIdx.x;
  const int xcd = bid & 7, slot = bid >> 3;
  const int bh = xcd * 6 + (slot >> 4);
  const int qt = slot & 15;
  const int bloc = bh / 12, h = bh % 12;
  const long rowbase = (long)bloc * 2048;

  // stage Q tile into Ps (one-time; vectorized VGPR path, padded)
#pragma unroll
  for (int it = 0; it < 4; ++it) {
    int c = tid + it * 256;
    int m = c >> 3, off = (c & 7) * 8;
    *(u16x8*)&Ps[m * LQ + off] =
        *(const u16x8*)&qk[(rowbase + qt * 128 + m) * 1536 + h * 64 + off];
  }
  __syncthreads();

  bf16x8 aq[2][2];
#pragma unroll
  for (int kk = 0; kk < 2; ++kk)
#pragma unroll
    for (int i = 0; i < 2; ++i)
      aq[kk][i] = *(const bf16x8*)&Ps[(wave * 32 + i * 16 + l16) * LQ +
                                      kk * 32 + quad * 8];

  bf16x8 ones;
#pragma unroll
  for (int q = 0; q < 8; ++q) ones[q] = (__bf16)1.0f;

  // glds staging: lane l -> tile row wave*16+(l>>3), logical chunk
  // ((l&7)^(l>>3)), phys chunk l&7; second glds covers rows +8.
  const int trow = lane >> 3;
  const int tcol = ((lane & 7) ^ trow) * 8;
  const u16* kg = qk + (rowbase + wave * 16 + trow) * 1536 + 768 + h * 64 + tcol;
  const u16* vg = vt + (long)(h * 64 + wave * 16 + trow) * 8192 + rowbase + tcol;
  u16* kl = Ks + wave * 1024;
  u16* vl = Vs + wave * 1024;
  const int sw = l16 & 7;

  f32x4 o[2][4] = {};
  f32x4 l_acc[2] = {};

  for (int t = 0; t < 32; ++t) {
    const long kvK = (long)t * 64 * 1536;
    const long kvV = (long)t * 64;
    glds16(kg + kvK, kl);
    glds16(kg + kvK + 8 * 1536, kl + 512);
    glds16(vg + kvV, vl);
    glds16(vg + kvV + 8 * 8192, vl + 512);
    __syncthreads();

    // S^T = K @ Q^T : col=l16=qrow_local, row=quad*4+r=s_local
    f32x4 sc[4][2] = {};
#pragma unroll
    for (int kk = 0; kk < 2; ++kk) {
      bf16x8 bk[4];
#pragma unroll
      for (int j = 0; j < 4; ++j)
        bk[j] = *(const bf16x8*)&Ks[(j * 16 + l16) * 64 +
                                    ((kk * 4 + quad) ^ sw) * 8];
#pragma unroll
      for (int j = 0; j < 4; ++j)
#pragma unroll
        for (int i = 0; i < 2; ++i)
          sc[j][i] = __builtin_amdgcn_mfma_f32_16x16x32_bf16(bk[j], aq[kk][i],
                                                             sc[j][i], 0, 0, 0);
    }

    // P[qrow][s] = exp2(S * 0.125*log2 e); packed b64 writes (wave-private)
#pragma unroll
    for (int i = 0; i < 2; ++i)
#pragma unroll
      for (int j = 0; j < 4; ++j) {
        f32x4 p;
#pragma unroll
        for (int r = 0; r < 4; ++r)
          p[r] = exp2f(sc[j][i][r] * 0.18033688011112042f);
        *(bf16x4*)&Ps[(wave * 32 + i * 16 + l16) * LQ + j * 16 + quad * 4] =
            __builtin_convertvector(p, bf16x4);
      }

    // O += P @ V ; l += 1 @ P
#pragma unroll
    for (int kk = 0; kk < 2; ++kk) {
      bf16x8 ap[2], bv[4];
#pragma unroll
      for (int i = 0; i < 2; ++i)
        ap[i] = *(const bf16x8*)&Ps[(wave * 32 + i * 16 + l16) * LQ + kk * 32 +
                                    quad * 8];
#pragma unroll
      for (int n = 0; n < 4; ++n)
        bv[n] = *(const bf16x8*)&Vs[(n * 16 + l16) * 64 +
                                    ((kk * 4 + quad) ^ sw) * 8];
#pragma unroll
      for (int i = 0; i < 2; ++i) {
        l_acc[i] = __builtin_amdgcn_mfma_f32_16x16x32_bf16(ones, ap[i],
                                                           l_acc[i], 0, 0, 0);
#pragma unroll
        for (int n = 0; n < 4; ++n)
          o[i][n] = __builtin_amdgcn_mfma_f32_16x16x32_bf16(ap[i], bv[n],
                                                            o[i][n], 0, 0, 0);
      }
    }
    __syncthreads();
  }

  // epilogue: O/l -> attnb[8192][768]
#pragma unroll
  for (int i = 0; i < 2; ++i) {
    f32x4 inv;
#pragma unroll
    for (int r = 0; r < 4; ++r)
      inv[r] = 1.0f / __shfl(l_acc[i][0], quad * 4 + r, 64);
#pragma unroll
    for (int n = 0; n < 4; ++n)
#pragma unroll
      for (int r = 0; r < 4; ++r) {
        int srow = qt * 128 + wave * 32 + i * 16 + quad * 4 + r;
        ((__bf16*)attnb)[(rowbase + srow) * 768 + h * 64 + n * 16 + l16] =
            (__bf16)(o[i][n][r] * inv[r]);
      }
  }
}

extern "C" void kernel_launch(void* const* d_in, const int* in_sizes, int n_in,
                              void* d_out, int out_size, void* d_ws,
                              size_t ws_size, hipStream_t stream) {
  const float* x = (const float*)d_in[0];      // [4,2048,768] fp32
  const float* w_qkv = (const float*)d_in[1];  // [768,2304] fp32
  const float* w_out = (const float*)d_in[2];  // [768,768] fp32
  const float* b_out = (const float*)d_in[3];  // [768] fp32
  float* out = (float*)d_out;                  // [4,2048,768] fp32

  // ws (29,884,416 B, proven):
  //   wqkvT [2304][768] bf16   3,538,944
  //   woutT [768][768]  bf16   1,179,648
  //   vt    [768][8192] bf16  12,582,912
  //   xb/attnb (aliased)      12,582,912  -- xb consumed by qkvt_k, then
  //                                          attn_k overwrites with attnb
  // qk [8192][1536] bf16 (25,165,824 B) lives in d_out until gemm2 overwrites.
  char* ws = (char*)d_ws;
  u16* wqkvT = (u16*)(ws);
  u16* woutT = (u16*)(ws + 3538944);
  u16* vt = (u16*)(ws + 4718592);
  u16* xb = (u16*)(ws + 17301504);
  u16* attnb = xb;
  u16* qkb = (u16*)d_out;

  prep_k<<<768, 256, 0, stream>>>(w_qkv, w_out, x, wqkvT, woutT, xb);
  qkvt_k<<<1152, 256, 0, stream>>>(xb, wqkvT, qkb, vt);
  attn_k<<<768, 256, 0, stream>>>(qkb, vt, attnb);
  gemm2_k<<<dim3(6, 64), 256, 0, stream>>>(attnb, woutT, out, b_out);
}